// Round 7
// baseline (6282.083 us; speedup 1.0000x reference)
//
#include <hip/hip_runtime.h>
#include <math.h>

#define TT 2048
#define NSLOT 6

// ---- d_ws layout (bytes) ----
// [0, 786432)    board: u64 [6 slot][128 g][128 q], q = {h[2q],h[2q+1], tag32}
// [786432, +8K)  fB: int per group, stride 64 B (M1 receipt: consumed h1 idx + 1)
#define FB_OFF  786432
#define ZERO_F4 49664          // (786432 + 8192) / 16

// ---- dynamic LDS (halves), TRANSPOSED weight layout [chunk][lane][8]:
// per-lane stride = 16 B -> banks 4l mod 32 -> 8-cycle floor, conflict-free.
// M0: lw [16 rc][512 tid][8] = 65536 h | X0 [2][256] @ 65536
// M1: lw2 [12 c][512][8] = 49152 h | lw3 [6 c][512][8] @ 49152 | X1 [2][512] @ 73728
#define M0_X   65536
#define M1_LW3 49152
#define M1_X   73728
#define LDS_BYTES 149504       // 74752 halves (M1); forces 1 block/CU

typedef _Float16 half2v __attribute__((ext_vector_type(2)));
typedef _Float16 half4v __attribute__((ext_vector_type(4)));
typedef _Float16 half8v __attribute__((ext_vector_type(8)));
typedef unsigned long long u64;
typedef unsigned int u32;

#if defined(__has_builtin)
#if __has_builtin(__builtin_amdgcn_fdot2)
#define HAVE_FDOT2 1
#endif
#endif

__device__ __forceinline__ float fdot2f(half2v a, half2v b, float c) {
#ifdef HAVE_FDOT2
    return __builtin_amdgcn_fdot2(a, b, c, false);
#else
    return c + (float)a.x * (float)b.x + (float)a.y * (float)b.y;
#endif
}
__device__ __forceinline__ half2v h2at(half8v v, int m) {
    half2v r; r.x = v[2 * m]; r.y = v[2 * m + 1]; return r;
}
__device__ __forceinline__ float dot8(half8v w, half8v x, float a) {
#pragma unroll
    for (int m = 0; m < 4; ++m) a = fdot2f(h2at(w, m), h2at(x, m), a);
    return a;
}
__device__ __forceinline__ half2v h2lo(half4v v) { half2v r; r.x = v[0]; r.y = v[1]; return r; }
__device__ __forceinline__ half2v h2hi(half4v v) { half2v r; r.x = v[2]; r.y = v[3]; return r; }

__device__ __forceinline__ float sigf(float x) { return 1.0f / (1.0f + __expf(-x)); }
__device__ __forceinline__ float tanh_f(float x) {
    float t = __expf(fminf(2.0f * x, 30.0f));
    return (t - 1.0f) / (t + 1.0f);
}
template<int CTRL, int XM>
__device__ __forceinline__ float xadd(float v) {
#if __has_builtin(__builtin_amdgcn_mov_dpp)
    int t = __builtin_amdgcn_mov_dpp(__builtin_bit_cast(int, v), CTRL, 0xF, 0xF, true);
    return v + __builtin_bit_cast(float, t);
#else
    return v + __shfl_xor(v, XM, 64);
#endif
}
__device__ __forceinline__ float xadd4(float v) {
#if __has_builtin(__builtin_amdgcn_ds_swizzle)
    int t = __builtin_amdgcn_ds_swizzle(__builtin_bit_cast(int, v), 0x101F);
    return v + __builtin_bit_cast(float, t);
#else
    return v + __shfl_xor(v, 4, 64);
#endif
}
__device__ __forceinline__ _Float16 lstm_fin(float g0, float g1, float g2, float g3, float& c) {
    float ig = sigf(g0), fg = sigf(g1), gg = tanh_f(g2), og = sigf(g3);
    float cn = fmaf(fg, c, ig * gg); c = cn;
    return (_Float16)(og * tanh_f(cn));
}
__device__ __forceinline__ int aload(const int* p) {
    return __hip_atomic_load((int*)p, __ATOMIC_RELAXED, __HIP_MEMORY_SCOPE_AGENT);
}
__device__ __forceinline__ void apost(int* p, int v) {
    __hip_atomic_store(p, v, __ATOMIC_RELAXED, __HIP_MEMORY_SCOPE_AGENT);
}
__device__ __forceinline__ u64 aload64(const u64* p) {
    return __hip_atomic_load((u64*)p, __ATOMIC_RELAXED, __HIP_MEMORY_SCOPE_AGENT);
}
__device__ __forceinline__ void astore64(u64* p, u64 v) {
    __hip_atomic_store(p, v, __ATOMIC_RELAXED, __HIP_MEMORY_SCOPE_AGENT);
}

__global__ __launch_bounds__(256)
void prep_zero(float4* ws) {
    int idx = blockIdx.x * 256 + threadIdx.x;
    if (idx < ZERO_F4) ws[idx] = make_float4(0.f, 0.f, 0.f, 0.f);
}

__global__ __launch_bounds__(512, 1)
void lstm_v8(const float* __restrict__ inp,
             const float* __restrict__ w1ih, const float* __restrict__ w1hh,
             const float* __restrict__ b1ih, const float* __restrict__ b1hh,
             const float* __restrict__ w2ih, const float* __restrict__ w2hh,
             const float* __restrict__ b2ih, const float* __restrict__ b2hh,
             const float* __restrict__ w3ih, const float* __restrict__ w3hh,
             const float* __restrict__ b3ih, const float* __restrict__ b3hh,
             const float* __restrict__ w4ih, const float* __restrict__ w4hh,
             const float* __restrict__ b4ih, const float* __restrict__ b4hh,
             const float* __restrict__ w5ih, const float* __restrict__ w5hh,
             const float* __restrict__ b5ih, const float* __restrict__ b5hh,
             const float* __restrict__ wlin, const float* __restrict__ blin,
             float* __restrict__ out, char* __restrict__ wsb)
{
    extern __shared__ __align__(16) _Float16 smem[];
    const int tid  = threadIdx.x;
    const int lane = tid & 63;
    const int wave = tid >> 6;
    const int g = blockIdx.x >> 1;          // group = batch element (0..127)
    u64* board = (u64*)wsb;
    int* fBp = (int*)(wsb + FB_OFF) + g * 16;

    if ((blockIdx.x & 1) == 0) {
        // ========================= M0 : layer 1 =========================
        _Float16* lw = smem;                 // [16 rc][512][8] transposed
        _Float16* X0 = smem + M0_X;          // [2][256] h1 state, double-buffered
        const int kg = tid & 3, slot = tid >> 2;   // KG=4, 128 slots x 2 units
        const int du = kg & 1;

        half8v w[6][8];                      // rows: gate(0..2) x unit(0,1)
#pragma unroll
        for (int r = 0; r < 6; ++r) {
            const int grow = (r >> 1) * 256 + slot * 2 + (r & 1);
#pragma unroll
            for (int j = 0; j < 8; ++j) {
                half8v t;
#pragma unroll
                for (int e = 0; e < 8; ++e)
                    t[e] = (_Float16)w1hh[grow * 256 + kg * 64 + j * 8 + e];
                w[r][j] = t;
            }
        }
        for (int rr = 0; rr < 2; ++rr) {     // gate-3 rows -> LDS (transposed)
            const int grow = 3 * 256 + slot * 2 + rr;
            for (int e = 0; e < 64; ++e)
                lw[(size_t)((rr * 8 + (e >> 3)) * 512 + tid) * 8 + (e & 7)] =
                    (_Float16)w1hh[grow * 256 + kg * 64 + e];
        }
        float b4[4], wx4[4];
#pragma unroll
        for (int gg = 0; gg < 4; ++gg) {
            const int gr = gg * 256 + slot * 2 + du;
            b4[gg] = b1ih[gr] + b1hh[gr];
            wx4[gg] = w1ih[gr];
        }
        for (int i = tid; i < 512; i += 512) X0[i] = (_Float16)0.f;
        __syncthreads();

        float c1 = 0.f;
        float xcur = inp[(size_t)g * TT];
        int fc = 0, fnew = 0;
        const _Float16* lwp = lw + tid * 8;  // chunk c: +c*4096; row1: +32768

        for (int s = 0; s <= 2048; ++s) {
            const int ph = s & 1, nph = ph ^ 1;

            // wave0: pack h1(s-1) -> board (tagged; fire-and-forget)
            if (wave == 0 && s >= 1) {
                if (s >= 7 && fc < s - 5) {          // 6-slot WAR back-pressure
                    do { fc = aload(fBp); } while (fc < s - 5);
                }
                u64 hv = *(const u64*)(X0 + ph * 256 + lane * 4);
                u64* dst = board + ((size_t)((s - 1) % NSLOT) * 128 + g) * 128 + lane * 2;
                const u64 tg = (u64)(u32)s << 32;    // tag for h1(s-1) = s
                astore64(dst,     (hv & 0xffffffffull) | tg);
                astore64(dst + 1, (hv >> 32)           | tg);
                fnew = aload(fBp);                   // pre-issued; used next step
            }

            if (s < 2048) {
                const float xt = xcur;
                if (s + 1 < 2048) xcur = inp[(size_t)g * TT + s + 1];
                float acc[8];
#pragma unroll
                for (int r = 0; r < 8; ++r) acc[r] = 0.f;
#pragma unroll
                for (int c = 0; c < 8; ++c) {        // 8-half chunks of x = h1(s-1)
                    const half8v xa = *(const half8v*)(X0 + ph * 256 + kg * 64 + c * 8);
#pragma unroll
                    for (int r = 0; r < 6; ++r)
                        acc[r] = dot8(w[r][c], xa, acc[r]);
                    const half8v la = *(const half8v*)(lwp + c * 4096);
                    acc[6] = dot8(la, xa, acc[6]);
                    const half8v ma = *(const half8v*)(lwp + 32768 + c * 4096);
                    acc[7] = dot8(ma, xa, acc[7]);
                }
#pragma unroll
                for (int r = 0; r < 8; ++r) {
                    float a = acc[r];
                    a = xadd<0xB1, 1>(a);            // xor1 (dpp)
                    a = xadd<0x4E, 2>(a);            // xor2 (dpp)
                    acc[r] = a;
                }
                if (kg < 2) {                        // one lane per unit
                    float g0 = fmaf(wx4[0], xt, acc[0 + kg] + b4[0]);
                    float g1 = fmaf(wx4[1], xt, acc[2 + kg] + b4[1]);
                    float g2 = fmaf(wx4[2], xt, acc[4 + kg] + b4[2]);
                    float g3 = fmaf(wx4[3], xt, acc[6 + kg] + b4[3]);
                    X0[nph * 256 + slot * 2 + kg] = lstm_fin(g0, g1, g2, g3, c1);
                }
            }
            __syncthreads();
            if (fnew > fc) fc = fnew;
        }
        return;
    }

    // ========================= M1 : layers 2..5 + head =========================
    _Float16* lw2 = smem;                    // [12 c][512][8] (L2 gate-3 row)
    _Float16* lw3 = smem + M1_LW3;           // [6 c][512][8] (L3 2nd row)
    _Float16* X1  = smem + M1_X;             // [2][512]: h1 0..256|h2 256..384|h3 384..448|h4 448..480|h5 480..496
    const int kg = tid & 3;
    const int unit2 = tid >> 2;              // 0..127
    const int unit3 = tid >> 3;              // 0..63
    const int sub = (tid >> 2) & 1;

    half8v w2[3][12];                        // L2 gates 0..2
#pragma unroll
    for (int r = 0; r < 3; ++r) {
        const int grow = r * 128 + unit2;
#pragma unroll
        for (int j = 0; j < 12; ++j) {
            half8v t;
#pragma unroll
            for (int e = 0; e < 8; ++e) {
                const int k = kg * 96 + j * 8 + e;
                t[e] = (_Float16)((k < 256) ? w2ih[grow * 256 + k]
                                            : w2hh[grow * 128 + (k - 256)]);
            }
            w2[r][j] = t;
        }
    }
    {
        const int grow = 3 * 128 + unit2;    // L2 gate-3 -> LDS (transposed)
        for (int e = 0; e < 96; ++e) {
            const int k = kg * 96 + e;
            lw2[(size_t)((e >> 3) * 512 + tid) * 8 + (e & 7)] =
                (_Float16)((k < 256) ? w2ih[grow * 256 + k]
                                     : w2hh[grow * 128 + (k - 256)]);
        }
    }
    half8v w3[6];                            // L3 row A (gate sub*2)
    {
        const int grow = (sub * 2) * 64 + unit3;
#pragma unroll
        for (int j = 0; j < 6; ++j) {
            half8v t;
            for (int e = 0; e < 8; ++e) {
                const int k = kg * 48 + j * 8 + e;
                t[e] = (_Float16)((k < 128) ? w3ih[grow * 128 + k]
                                            : w3hh[grow * 64 + (k - 128)]);
            }
            w3[j] = t;
        }
        const int grow1 = (sub * 2 + 1) * 64 + unit3;   // row B -> LDS (transposed)
        for (int e = 0; e < 48; ++e) {
            const int k = kg * 48 + e;
            lw3[(size_t)((e >> 3) * 512 + tid) * 8 + (e & 7)] =
                (_Float16)((k < 128) ? w3ih[grow1 * 128 + k]
                                     : w3hh[grow1 * 64 + (k - 128)]);
        }
    }
    half2v wt[4][6];                         // L4 (lanes 128..383) / L5 (384..447)
    float bt[4] = {0.f, 0.f, 0.f, 0.f};
    if (tid >= 128 && tid < 384) {
        const int l = tid - 128, unit4 = l >> 3, kg8 = l & 7;
#pragma unroll
        for (int gg = 0; gg < 4; ++gg) {
            const int grow = gg * 32 + unit4;
#pragma unroll
            for (int m = 0; m < 6; ++m) {
                half2v t;
                for (int e = 0; e < 2; ++e) {
                    const int k = kg8 * 12 + m * 2 + e;
                    t[e] = (_Float16)((k < 64) ? w4ih[grow * 64 + k]
                                               : w4hh[grow * 32 + (k - 64)]);
                }
                wt[gg][m] = t;
            }
            bt[gg] = b4ih[grow] + b4hh[grow];
        }
    } else if (tid >= 384 && tid < 448) {
        const int l = tid - 384, unit5 = l >> 2, kg5 = l & 3;
#pragma unroll
        for (int gg = 0; gg < 4; ++gg) {
            const int grow = gg * 16 + unit5;
#pragma unroll
            for (int m = 0; m < 6; ++m) {
                half2v t;
                for (int e = 0; e < 2; ++e) {
                    const int k = kg5 * 12 + m * 2 + e;
                    t[e] = (_Float16)((k < 32) ? w5ih[grow * 32 + k]
                                               : w5hh[grow * 16 + (k - 32)]);
                }
                wt[gg][m] = t;
            }
            bt[gg] = b5ih[grow] + b5hh[grow];
        }
    }
    float b2v[4], b3v[4];
#pragma unroll
    for (int gg = 0; gg < 4; ++gg) {
        b2v[gg] = b2ih[gg * 128 + unit2] + b2hh[gg * 128 + unit2];
        b3v[gg] = b3ih[gg * 64 + unit3] + b3hh[gg * 64 + unit3];
    }
    float wlj = 0.f, blv = 0.f;
    if (tid >= 448 && tid < 464) { wlj = wlin[tid - 448]; blv = blin[0]; }

    for (int i = tid; i < 1024; i += 512) X1[i] = (_Float16)0.f;
    __syncthreads();
    if (wave == 7) {                         // prologue: stage h1(0) (tag 1)
        const u64* src = board + (size_t)g * 128 + 2 * lane;
        u64 a, b;
        do { a = aload64(src); b = aload64(src + 1); }
        while (!__all(((u32)(a >> 32) == 1u) && ((u32)(b >> 32) == 1u)));
        *(u64*)(X1 + 4 * lane) = (u64)(u32)a | ((u64)(u32)b << 32);
    }
    __syncthreads();

    float c2 = 0.f, c3 = 0.f, ct = 0.f;
    for (int t = 0; t <= 2051; ++t) {
        const int ph = t & 1, nph = ph ^ 1;
        u64 pa = 0, pb = 0;
        const bool dopf = (t + 1 <= 2047);
        const u64* psrc = board + ((size_t)((t + 1) % NSLOT) * 128 + g) * 128 + 2 * lane;
        if (wave == 7 && dopf) { pa = aload64(psrc); pb = aload64(psrc + 1); }  // prefetch h1(t+1)

        // ---- L2 computes h2(t) ----
        if (t <= 2047) {
            float a0 = 0.f, a1 = 0.f, a2 = 0.f, a3 = 0.f;
#pragma unroll
            for (int c = 0; c < 12; ++c) {
                const half8v xa = *(const half8v*)(X1 + ph * 512 + kg * 96 + c * 8);
                a0 = dot8(w2[0][c], xa, a0);
                a1 = dot8(w2[1][c], xa, a1);
                a2 = dot8(w2[2][c], xa, a2);
                const half8v la = *(const half8v*)(lw2 + (size_t)(c * 512 + tid) * 8);
                a3 = dot8(la, xa, a3);
            }
            a0 = xadd<0xB1,1>(a0); a0 = xadd<0x4E,2>(a0);
            a1 = xadd<0xB1,1>(a1); a1 = xadd<0x4E,2>(a1);
            a2 = xadd<0xB1,1>(a2); a2 = xadd<0x4E,2>(a2);
            a3 = xadd<0xB1,1>(a3); a3 = xadd<0x4E,2>(a3);
            if (kg == 0)
                X1[nph * 512 + 256 + unit2] =
                    lstm_fin(a0 + b2v[0], a1 + b2v[1], a2 + b2v[2], a3 + b2v[3], c2);
        }
        // ---- L3 computes h3(t-1) ----
        if (t >= 1 && t <= 2048) {
            float sA = 0.f, sB = 0.f;
#pragma unroll
            for (int c = 0; c < 6; ++c) {
                const half8v xa = *(const half8v*)(X1 + ph * 512 + 256 + kg * 48 + c * 8);
                sA = dot8(w3[c], xa, sA);
                const half8v la = *(const half8v*)(lw3 + (size_t)(c * 512 + tid) * 8);
                sB = dot8(la, xa, sB);
            }
            sA = xadd<0xB1,1>(sA); sA = xadd<0x4E,2>(sA);
            sB = xadd<0xB1,1>(sB); sB = xadd<0x4E,2>(sB);
            const float sA2 = __shfl_xor(sA, 4, 64);
            const float sB2 = __shfl_xor(sB, 4, 64);
            if (kg == 0 && sub == 0)
                X1[nph * 512 + 384 + unit3] =
                    lstm_fin(sA + b3v[0], sB + b3v[1], sA2 + b3v[2], sB2 + b3v[3], c3);
        }
        // ---- L4 computes h4(t-2): lanes 128..383 (KG=8) ----
        if (tid >= 128 && tid < 384 && t >= 2 && t <= 2049) {
            const int l = tid - 128, kg8 = l & 7, unit4 = l >> 3;
            const _Float16* xp = X1 + ph * 512 + 384 + kg8 * 12;
            const half4v x0 = *(const half4v*)(xp);
            const half4v x1 = *(const half4v*)(xp + 4);
            const half4v x2 = *(const half4v*)(xp + 8);
            float a[4] = {0.f, 0.f, 0.f, 0.f};
#pragma unroll
            for (int gg = 0; gg < 4; ++gg) {
                a[gg] = fdot2f(wt[gg][0], h2lo(x0), a[gg]);
                a[gg] = fdot2f(wt[gg][1], h2hi(x0), a[gg]);
                a[gg] = fdot2f(wt[gg][2], h2lo(x1), a[gg]);
                a[gg] = fdot2f(wt[gg][3], h2hi(x1), a[gg]);
                a[gg] = fdot2f(wt[gg][4], h2lo(x2), a[gg]);
                a[gg] = fdot2f(wt[gg][5], h2hi(x2), a[gg]);
            }
#pragma unroll
            for (int gg = 0; gg < 4; ++gg) {
                float v = a[gg];
                v = xadd<0xB1,1>(v); v = xadd<0x4E,2>(v); v = xadd4(v);
                a[gg] = v;
            }
            if (kg8 == 0)
                X1[nph * 512 + 448 + unit4] =
                    lstm_fin(a[0] + bt[0], a[1] + bt[1], a[2] + bt[2], a[3] + bt[3], ct);
        }
        // ---- L5 computes h5(t-3): lanes 384..447 (KG=4) ----
        if (tid >= 384 && tid < 448 && t >= 3 && t <= 2050) {
            const int l = tid - 384, kg5 = l & 3, unit5 = l >> 2;
            const _Float16* xp = X1 + ph * 512 + 448 + kg5 * 12;
            const half4v x0 = *(const half4v*)(xp);
            const half4v x1 = *(const half4v*)(xp + 4);
            const half4v x2 = *(const half4v*)(xp + 8);
            float a[4] = {0.f, 0.f, 0.f, 0.f};
#pragma unroll
            for (int gg = 0; gg < 4; ++gg) {
                a[gg] = fdot2f(wt[gg][0], h2lo(x0), a[gg]);
                a[gg] = fdot2f(wt[gg][1], h2hi(x0), a[gg]);
                a[gg] = fdot2f(wt[gg][2], h2lo(x1), a[gg]);
                a[gg] = fdot2f(wt[gg][3], h2hi(x1), a[gg]);
                a[gg] = fdot2f(wt[gg][4], h2lo(x2), a[gg]);
                a[gg] = fdot2f(wt[gg][5], h2hi(x2), a[gg]);
            }
#pragma unroll
            for (int gg = 0; gg < 4; ++gg) {
                float v = a[gg];
                v = xadd<0xB1,1>(v); v = xadd<0x4E,2>(v);
                a[gg] = v;
            }
            if (kg5 == 0)
                X1[nph * 512 + 480 + unit5] =
                    lstm_fin(a[0] + bt[0], a[1] + bt[1], a[2] + bt[2], a[3] + bt[3], ct);
        }
        // ---- head outputs y(t-4) (wave7, 16 lanes) ----
        if (wave == 7 && lane < 16 && t >= 4) {
            float p = wlj * (float)X1[ph * 512 + 480 + lane];
            p += __shfl_xor(p, 1, 64); p += __shfl_xor(p, 2, 64);
            p += __shfl_xor(p, 4, 64); p += __shfl_xor(p, 8, 64);
            if (lane == 0) out[(size_t)g * TT + (t - 4)] = p + blv;
        }
        // ---- stage commit: h1(t+1) -> X1[next phase]; post receipt ----
        if (wave == 7 && dopf) {
            const u32 want = (u32)(t + 2);
            while (!__all(((u32)(pa >> 32) == want) && ((u32)(pb >> 32) == want))) {
                pa = aload64(psrc); pb = aload64(psrc + 1);
            }
            *(u64*)(X1 + nph * 512 + 4 * lane) = (u64)(u32)pa | ((u64)(u32)pb << 32);
            if (lane == 0) apost(fBp, t + 2);
        }
        __syncthreads();
    }
}

extern "C" void kernel_launch(void* const* d_in, const int* in_sizes, int n_in,
                              void* d_out, int out_size, void* d_ws, size_t ws_size,
                              hipStream_t stream) {
    const float* p[23];
    for (int i = 0; i < 23 && i < n_in; ++i) p[i] = (const float*)d_in[i];

    (void)hipFuncSetAttribute((const void*)lstm_v8,
                              hipFuncAttributeMaxDynamicSharedMemorySize,
                              LDS_BYTES);

    prep_zero<<<dim3((ZERO_F4 + 255) / 256), dim3(256), 0, stream>>>((float4*)d_ws);

    // grid 256 = CU count; ~146 KB LDS -> 1 block/CU -> all M0/M1 pairs co-resident.
    lstm_v8<<<dim3(256), dim3(512), LDS_BYTES, stream>>>(
        p[0],
        p[1],  p[2],  p[3],  p[4],
        p[5],  p[6],  p[7],  p[8],
        p[9],  p[10], p[11], p[12],
        p[13], p[14], p[15], p[16],
        p[17], p[18], p[19], p[20],
        p[21], p[22],
        (float*)d_out, (char*)d_ws);
}

// Round 8
// 5691.018 us; speedup vs baseline: 1.1039x; 1.1039x over previous
//
#include <hip/hip_runtime.h>
#include <math.h>

#define TT 2048
#define NSLOT 6

// ---- d_ws layout (bytes) ----
// [0, 786432)    board: u64 [6 slot][128 g][128 q], q = {h[2q],h[2q+1], tag32}
// [786432, +8K)  fB: int per group, stride 64 B (M1 receipt: consumed h1 idx + 1)
#define FB_OFF  786432
#define ZERO_F4 49664          // (786432 + 8192) / 16

// ---- dynamic LDS (halves) ----
// M0: A1lds [18 frag][512 tid][8] = 73728 h | X0 [2][256] @73728 | G1 f32[4][256] @74240
// M1: A2lds [12 frag][512 tid][8] = 49152 h | lw3 [6][512][8] @49152 | X1 [2][512] @73728
//     | G2 f32[4][128] @74752
#define M0_X    73728
#define M0_G    74240
#define M1_LW3  49152
#define M1_X    73728
#define M1_G    74752
#define LDS_BYTES 153600       // >80KB -> 1 block/CU (protocol needs all 256 co-resident)

typedef _Float16 half2v __attribute__((ext_vector_type(2)));
typedef _Float16 half4v __attribute__((ext_vector_type(4)));
typedef _Float16 half8v __attribute__((ext_vector_type(8)));
typedef float f32x4 __attribute__((ext_vector_type(4)));
typedef unsigned long long u64;
typedef unsigned int u32;

#if defined(__has_builtin)
#if __has_builtin(__builtin_amdgcn_fdot2)
#define HAVE_FDOT2 1
#endif
#endif

__device__ __forceinline__ float fdot2f(half2v a, half2v b, float c) {
#ifdef HAVE_FDOT2
    return __builtin_amdgcn_fdot2(a, b, c, false);
#else
    return c + (float)a.x * (float)b.x + (float)a.y * (float)b.y;
#endif
}
__device__ __forceinline__ half2v h2at(half8v v, int m) {
    half2v r; r.x = v[2 * m]; r.y = v[2 * m + 1]; return r;
}
__device__ __forceinline__ float dot8(half8v w, half8v x, float a) {
#pragma unroll
    for (int m = 0; m < 4; ++m) a = fdot2f(h2at(w, m), h2at(x, m), a);
    return a;
}
__device__ __forceinline__ half2v h2lo(half4v v) { half2v r; r.x = v[0]; r.y = v[1]; return r; }
__device__ __forceinline__ half2v h2hi(half4v v) { half2v r; r.x = v[2]; r.y = v[3]; return r; }

__device__ __forceinline__ float sigf(float x) { return 1.0f / (1.0f + __expf(-x)); }
__device__ __forceinline__ float tanh_f(float x) {
    float t = __expf(fminf(2.0f * x, 30.0f));
    return (t - 1.0f) / (t + 1.0f);
}
template<int CTRL, int XM>
__device__ __forceinline__ float xadd(float v) {
#if __has_builtin(__builtin_amdgcn_mov_dpp)
    int t = __builtin_amdgcn_mov_dpp(__builtin_bit_cast(int, v), CTRL, 0xF, 0xF, true);
    return v + __builtin_bit_cast(float, t);
#else
    return v + __shfl_xor(v, XM, 64);
#endif
}
__device__ __forceinline__ _Float16 lstm_fin(float g0, float g1, float g2, float g3, float& c) {
    float ig = sigf(g0), fg = sigf(g1), gg = tanh_f(g2), og = sigf(g3);
    float cn = fmaf(fg, c, ig * gg); c = cn;
    return (_Float16)(og * tanh_f(cn));
}
__device__ __forceinline__ int aload(const int* p) {
    return __hip_atomic_load((int*)p, __ATOMIC_RELAXED, __HIP_MEMORY_SCOPE_AGENT);
}
__device__ __forceinline__ void apost(int* p, int v) {
    __hip_atomic_store(p, v, __ATOMIC_RELAXED, __HIP_MEMORY_SCOPE_AGENT);
}
__device__ __forceinline__ u64 aload64(const u64* p) {
    return __hip_atomic_load((u64*)p, __ATOMIC_RELAXED, __HIP_MEMORY_SCOPE_AGENT);
}
__device__ __forceinline__ void astore64(u64* p, u64 v) {
    __hip_atomic_store(p, v, __ATOMIC_RELAXED, __HIP_MEMORY_SCOPE_AGENT);
}

// k-mapping inside a 32-wide k-tile for the 16x16x32 f16 MFMA operands.
// Any consistent bijection between A and B cancels in the contraction; this one
// matches the HW tr-read layout (two stacked K=16 halves).
__device__ __forceinline__ int kmap(int lane, int e) {
    return ((lane >> 4) << 2) + (e & 3) + ((e >> 2) << 4);
}

__global__ __launch_bounds__(256)
void prep_zero(float4* ws) {
    int idx = blockIdx.x * 256 + threadIdx.x;
    if (idx < ZERO_F4) ws[idx] = make_float4(0.f, 0.f, 0.f, 0.f);
}

__global__ __launch_bounds__(512, 1)
void lstm_v9(const float* __restrict__ inp,
             const float* __restrict__ w1ih, const float* __restrict__ w1hh,
             const float* __restrict__ b1ih, const float* __restrict__ b1hh,
             const float* __restrict__ w2ih, const float* __restrict__ w2hh,
             const float* __restrict__ b2ih, const float* __restrict__ b2hh,
             const float* __restrict__ w3ih, const float* __restrict__ w3hh,
             const float* __restrict__ b3ih, const float* __restrict__ b3hh,
             const float* __restrict__ w4ih, const float* __restrict__ w4hh,
             const float* __restrict__ b4ih, const float* __restrict__ b4hh,
             const float* __restrict__ w5ih, const float* __restrict__ w5hh,
             const float* __restrict__ b5ih, const float* __restrict__ b5hh,
             const float* __restrict__ wlin, const float* __restrict__ blin,
             float* __restrict__ out, char* __restrict__ wsb)
{
    extern __shared__ __align__(16) _Float16 smem[];
    const int tid  = threadIdx.x;
    const int lane = tid & 63;
    const int wave = tid >> 6;
    const int g = blockIdx.x >> 1;          // group = batch element (0..127)
    u64* board = (u64*)wsb;
    int* fBp = (int*)(wsb + FB_OFF) + g * 16;
    const int lrow = lane & 15;             // MFMA A row / D col index
    const int lblk = lane >> 4;             // MFMA k-block / D row-block index

    if ((blockIdx.x & 1) == 0) {
        // ========================= M0 : layer 1 (MFMA) =========================
        _Float16* A1lds = smem;              // [18][512][8]
        _Float16* X0 = smem + M0_X;          // [2][256] h1, double-buffered
        float*    G1 = (float*)(smem + M0_G);// [4][256] gate values

        // A-fragments: 64 tiles/wave = [j=rt-local 0..7][kt 0..7]; rt = wave*8+j
        // gate = rt>>4, ub = rt&15; row = ub*16 + lrow; k = kt*32 + kmap(lane,e)
        half8v Areg[46];
#pragma unroll
        for (int j = 0; j < 8; ++j) {
            const int rt = wave * 8 + j;
            const int grow = (rt >> 4) * 256 + (rt & 15) * 16 + lrow;
#pragma unroll
            for (int kt = 0; kt < 8; ++kt) {
                half8v a;
#pragma unroll
                for (int e = 0; e < 8; ++e)
                    a[e] = (_Float16)w1hh[grow * 256 + kt * 32 + kmap(lane, e)];
                const int fi = j * 8 + kt;
                if (fi < 46) Areg[fi < 46 ? fi : 0] = a;
                else *(half8v*)(A1lds + ((size_t)(fi - 46) * 512 + tid) * 8) = a;
            }
        }
        float b4[4] = {0.f,0.f,0.f,0.f}, wx4[4] = {0.f,0.f,0.f,0.f};
        if (tid < 256) {
#pragma unroll
            for (int gg = 0; gg < 4; ++gg) {
                b4[gg] = b1ih[gg * 256 + tid] + b1hh[gg * 256 + tid];
                wx4[gg] = w1ih[gg * 256 + tid];
            }
        }
        for (int i = tid; i < 512; i += 512) X0[i] = (_Float16)0.f;
        __syncthreads();

        float c1 = 0.f;
        float xcur = inp[(size_t)g * TT];
        int fc = 0, fnew = 0;

        for (int s = 0; s <= 2048; ++s) {
            const int ph = s & 1, nph = ph ^ 1;

            // wave0: pack h1(s-1) -> board (tagged; fire-and-forget)
            if (wave == 0 && s >= 1) {
                if (s >= 7 && fc < s - 5) {          // 6-slot WAR back-pressure
                    do { fc = aload(fBp); } while (fc < s - 5);
                }
                u64 hv = *(const u64*)(X0 + ph * 256 + lane * 4);
                u64* dst = board + ((size_t)((s - 1) % NSLOT) * 128 + g) * 128 + lane * 2;
                const u64 tg = (u64)(u32)s << 32;    // tag for h1(s-1) = s
                astore64(dst,     (hv & 0xffffffffull) | tg);
                astore64(dst + 1, (hv >> 32)           | tg);
                fnew = aload(fBp);                   // pre-issued; used next step
            }

            float xt = 0.f;
            if (s < 2048) {
                xt = xcur;
                if (s + 1 < 2048) xcur = inp[(size_t)g * TT + s + 1];

                f32x4 acc[8];
#pragma unroll
                for (int j = 0; j < 8; ++j) acc[j] = (f32x4){0.f,0.f,0.f,0.f};
#pragma unroll
                for (int kt = 0; kt < 8; ++kt) {
                    // broadcast-B: every lane holds the x chunk for its k-block
                    half4v xlo = *(const half4v*)(X0 + ph * 256 + kt * 32 + lblk * 4);
                    half4v xhi = *(const half4v*)(X0 + ph * 256 + kt * 32 + 16 + lblk * 4);
                    half8v b;
                    b[0]=xlo[0]; b[1]=xlo[1]; b[2]=xlo[2]; b[3]=xlo[3];
                    b[4]=xhi[0]; b[5]=xhi[1]; b[6]=xhi[2]; b[7]=xhi[3];
#pragma unroll
                    for (int j = 0; j < 8; ++j) {
                        const int fi = j * 8 + kt;
                        half8v a;
                        if (fi < 46) a = Areg[fi < 46 ? fi : 0];
                        else a = *(const half8v*)(A1lds + ((size_t)(fi - 46) * 512 + tid) * 8);
                        acc[j] = __builtin_amdgcn_mfma_f32_16x16x32_f16(a, b, acc[j], 0, 0, 0);
                    }
                }
                // D: row = lblk*4 + r, all 16 cols identical; lanes lrow==0 write G1
                if (lrow == 0) {
#pragma unroll
                    for (int j = 0; j < 8; ++j) {
                        const int rt = wave * 8 + j;
                        *(f32x4*)(G1 + (rt >> 4) * 256 + (rt & 15) * 16 + lblk * 4) = acc[j];
                    }
                }
            }
            __syncthreads();                         // G1 ready
            if (s < 2048 && tid < 256) {
                float g0 = G1[tid]       + b4[0];
                float g1 = G1[256 + tid] + b4[1];
                float g2 = G1[512 + tid] + b4[2];
                float g3 = G1[768 + tid] + b4[3];
                g0 = fmaf(wx4[0], xt, g0); g1 = fmaf(wx4[1], xt, g1);
                g2 = fmaf(wx4[2], xt, g2); g3 = fmaf(wx4[3], xt, g3);
                X0[nph * 256 + tid] = lstm_fin(g0, g1, g2, g3, c1);
            }
            __syncthreads();                         // X0[nph] ready
            if (fnew > fc) fc = fnew;
        }
        return;
    }

    // ========================= M1 : L2 (MFMA) + L3/L4/L5 + head =========================
    _Float16* A2lds = smem;                  // [12][512][8] (L2 rt-local 3)
    _Float16* lw3  = smem + M1_LW3;          // [6][512][8] (L3 2nd row)
    _Float16* X1   = smem + M1_X;            // [2][512]: h1 0..256|h2 256..384|h3 384..448|h4 448..480|h5 480..496
    float*    G2   = (float*)(smem + M1_G);  // [4][128]

    // L2 A-fragments: 48 tiles/wave = [rtL 0..3][kt 0..11]; rt = wave*4+rtL
    // gate = rt>>3, ub = rt&7; row = ub*16 + lrow; k = kt*32 + kmap
    half8v A2[36];
#pragma unroll
    for (int rtL = 0; rtL < 4; ++rtL) {
        const int rt = wave * 4 + rtL;
        const int grow = (rt >> 3) * 128 + (rt & 7) * 16 + lrow;
#pragma unroll
        for (int kt = 0; kt < 12; ++kt) {
            half8v a;
#pragma unroll
            for (int e = 0; e < 8; ++e) {
                const int k = kt * 32 + kmap(lane, e);
                a[e] = (_Float16)((k < 256) ? w2ih[grow * 256 + k]
                                            : w2hh[grow * 128 + (k - 256)]);
            }
            const int fi = rtL * 12 + kt;
            if (fi < 36) A2[fi < 36 ? fi : 0] = a;
            else *(half8v*)(A2lds + ((size_t)kt * 512 + tid) * 8) = a;
        }
    }
    // L3 weights (v8 layout): kg = tid&3, unit3 = tid>>3, sub = (tid>>2)&1
    const int kg = tid & 3;
    const int unit3 = tid >> 3;
    const int sub = (tid >> 2) & 1;
    half8v w3[6];
    {
        const int grow = (sub * 2) * 64 + unit3;
#pragma unroll
        for (int j = 0; j < 6; ++j) {
            half8v t;
            for (int e = 0; e < 8; ++e) {
                const int k = kg * 48 + j * 8 + e;
                t[e] = (_Float16)((k < 128) ? w3ih[grow * 128 + k]
                                            : w3hh[grow * 64 + (k - 128)]);
            }
            w3[j] = t;
        }
        const int grow1 = (sub * 2 + 1) * 64 + unit3;
        for (int e = 0; e < 48; ++e) {
            const int k = kg * 48 + e;
            lw3[(size_t)((e >> 3) * 512 + tid) * 8 + (e & 7)] =
                (_Float16)((k < 128) ? w3ih[grow1 * 128 + k]
                                     : w3hh[grow1 * 64 + (k - 128)]);
        }
    }
    half2v wt[4][6];
    float bt[4] = {0.f, 0.f, 0.f, 0.f};
    if (tid >= 128 && tid < 384) {
        const int l = tid - 128, unit4 = l >> 3, kg8 = l & 7;
#pragma unroll
        for (int gg = 0; gg < 4; ++gg) {
            const int grow = gg * 32 + unit4;
#pragma unroll
            for (int m = 0; m < 6; ++m) {
                half2v t;
                for (int e = 0; e < 2; ++e) {
                    const int k = kg8 * 12 + m * 2 + e;
                    t[e] = (_Float16)((k < 64) ? w4ih[grow * 64 + k]
                                               : w4hh[grow * 32 + (k - 64)]);
                }
                wt[gg][m] = t;
            }
            bt[gg] = b4ih[grow] + b4hh[grow];
        }
    } else if (tid >= 384 && tid < 448) {
        const int l = tid - 384, unit5 = l >> 2, kg5 = l & 3;
#pragma unroll
        for (int gg = 0; gg < 4; ++gg) {
            const int grow = gg * 16 + unit5;
#pragma unroll
            for (int m = 0; m < 6; ++m) {
                half2v t;
                for (int e = 0; e < 2; ++e) {
                    const int k = kg5 * 12 + m * 2 + e;
                    t[e] = (_Float16)((k < 32) ? w5ih[grow * 32 + k]
                                               : w5hh[grow * 16 + (k - 32)]);
                }
                wt[gg][m] = t;
            }
            bt[gg] = b5ih[grow] + b5hh[grow];
        }
    }
    float b2v[4] = {0.f,0.f,0.f,0.f}, b3v[4];
    if (tid < 128) {
#pragma unroll
        for (int gg = 0; gg < 4; ++gg)
            b2v[gg] = b2ih[gg * 128 + tid] + b2hh[gg * 128 + tid];
    }
#pragma unroll
    for (int gg = 0; gg < 4; ++gg)
        b3v[gg] = b3ih[gg * 64 + unit3] + b3hh[gg * 64 + unit3];
    float wlj = 0.f, blv = 0.f;
    if (tid >= 448 && tid < 464) { wlj = wlin[tid - 448]; blv = blin[0]; }

    for (int i = tid; i < 1024; i += 512) X1[i] = (_Float16)0.f;
    __syncthreads();
    if (wave == 7) {                         // prologue: stage h1(0) (tag 1)
        const u64* src = board + (size_t)g * 128 + 2 * lane;
        u64 a, b;
        do { a = aload64(src); b = aload64(src + 1); }
        while (!__all(((u32)(a >> 32) == 1u) && ((u32)(b >> 32) == 1u)));
        *(u64*)(X1 + 4 * lane) = (u64)(u32)a | ((u64)(u32)b << 32);
    }
    __syncthreads();

    float c2 = 0.f, c3 = 0.f, ct = 0.f;
    for (int t = 0; t <= 2051; ++t) {
        const int ph = t & 1, nph = ph ^ 1;
        u64 pa = 0, pb = 0;
        const bool dopf = (t + 1 <= 2047);
        const u64* psrc = board + ((size_t)((t + 1) % NSLOT) * 128 + g) * 128 + 2 * lane;
        if (wave == 7 && dopf) { pa = aload64(psrc); pb = aload64(psrc + 1); }

        // ---- L2 via MFMA: gates(t) from x=[h1(t); h2(t-1)] = X1[ph][0..384] ----
        if (t <= 2047) {
            f32x4 acc[4];
#pragma unroll
            for (int r = 0; r < 4; ++r) acc[r] = (f32x4){0.f,0.f,0.f,0.f};
#pragma unroll
            for (int kt = 0; kt < 12; ++kt) {
                half4v xlo = *(const half4v*)(X1 + ph * 512 + kt * 32 + lblk * 4);
                half4v xhi = *(const half4v*)(X1 + ph * 512 + kt * 32 + 16 + lblk * 4);
                half8v b;
                b[0]=xlo[0]; b[1]=xlo[1]; b[2]=xlo[2]; b[3]=xlo[3];
                b[4]=xhi[0]; b[5]=xhi[1]; b[6]=xhi[2]; b[7]=xhi[3];
#pragma unroll
                for (int rtL = 0; rtL < 4; ++rtL) {
                    const int fi = rtL * 12 + kt;
                    half8v a;
                    if (fi < 36) a = A2[fi < 36 ? fi : 0];
                    else a = *(const half8v*)(A2lds + ((size_t)kt * 512 + tid) * 8);
                    acc[rtL] = __builtin_amdgcn_mfma_f32_16x16x32_f16(a, b, acc[rtL], 0, 0, 0);
                }
            }
            if (lrow == 0) {
#pragma unroll
                for (int rtL = 0; rtL < 4; ++rtL) {
                    const int rt = wave * 4 + rtL;
                    *(f32x4*)(G2 + (rt >> 3) * 128 + (rt & 7) * 16 + lblk * 4) = acc[rtL];
                }
            }
        }
        // ---- L3 computes h3(t-1) (fdot2, v8) ----
        if (t >= 1 && t <= 2048) {
            float sA = 0.f, sB = 0.f;
#pragma unroll
            for (int c = 0; c < 6; ++c) {
                const half8v xa = *(const half8v*)(X1 + ph * 512 + 256 + kg * 48 + c * 8);
                sA = dot8(w3[c], xa, sA);
                const half8v la = *(const half8v*)(lw3 + (size_t)(c * 512 + tid) * 8);
                sB = dot8(la, xa, sB);
            }
            sA = xadd<0xB1,1>(sA); sA = xadd<0x4E,2>(sA);
            sB = xadd<0xB1,1>(sB); sB = xadd<0x4E,2>(sB);
            const float sA2 = __shfl_xor(sA, 4, 64);
            const float sB2 = __shfl_xor(sB, 4, 64);
            if (kg == 0 && sub == 0)
                X1[nph * 512 + 384 + unit3] =
                    lstm_fin(sA + b3v[0], sB + b3v[1], sA2 + b3v[2], sB2 + b3v[3], c3);
        }
        // ---- L4 computes h4(t-2): lanes 128..383 (KG=8, v8) ----
        if (tid >= 128 && tid < 384 && t >= 2 && t <= 2049) {
            const int l = tid - 128, kg8 = l & 7, unit4 = l >> 3;
            const _Float16* xp = X1 + ph * 512 + 384 + kg8 * 12;
            const half4v x0 = *(const half4v*)(xp);
            const half4v x1 = *(const half4v*)(xp + 4);
            const half4v x2 = *(const half4v*)(xp + 8);
            float a[4] = {0.f, 0.f, 0.f, 0.f};
#pragma unroll
            for (int gg = 0; gg < 4; ++gg) {
                a[gg] = fdot2f(wt[gg][0], h2lo(x0), a[gg]);
                a[gg] = fdot2f(wt[gg][1], h2hi(x0), a[gg]);
                a[gg] = fdot2f(wt[gg][2], h2lo(x1), a[gg]);
                a[gg] = fdot2f(wt[gg][3], h2hi(x1), a[gg]);
                a[gg] = fdot2f(wt[gg][4], h2lo(x2), a[gg]);
                a[gg] = fdot2f(wt[gg][5], h2hi(x2), a[gg]);
            }
#pragma unroll
            for (int gg = 0; gg < 4; ++gg) {
                float v = a[gg];
                v = xadd<0xB1,1>(v); v = xadd<0x4E,2>(v);
                v += __shfl_xor(v, 4, 64);
                a[gg] = v;
            }
            if (kg8 == 0)
                X1[nph * 512 + 448 + unit4] =
                    lstm_fin(a[0] + bt[0], a[1] + bt[1], a[2] + bt[2], a[3] + bt[3], ct);
        }
        // ---- L5 computes h5(t-3): lanes 384..447 (KG=4, v8) ----
        if (tid >= 384 && tid < 448 && t >= 3 && t <= 2050) {
            const int l = tid - 384, kg5 = l & 3, unit5 = l >> 2;
            const _Float16* xp = X1 + ph * 512 + 448 + kg5 * 12;
            const half4v x0 = *(const half4v*)(xp);
            const half4v x1 = *(const half4v*)(xp + 4);
            const half4v x2 = *(const half4v*)(xp + 8);
            float a[4] = {0.f, 0.f, 0.f, 0.f};
#pragma unroll
            for (int gg = 0; gg < 4; ++gg) {
                a[gg] = fdot2f(wt[gg][0], h2lo(x0), a[gg]);
                a[gg] = fdot2f(wt[gg][1], h2hi(x0), a[gg]);
                a[gg] = fdot2f(wt[gg][2], h2lo(x1), a[gg]);
                a[gg] = fdot2f(wt[gg][3], h2hi(x1), a[gg]);
                a[gg] = fdot2f(wt[gg][4], h2lo(x2), a[gg]);
                a[gg] = fdot2f(wt[gg][5], h2hi(x2), a[gg]);
            }
#pragma unroll
            for (int gg = 0; gg < 4; ++gg) {
                float v = a[gg];
                v = xadd<0xB1,1>(v); v = xadd<0x4E,2>(v);
                a[gg] = v;
            }
            if (kg5 == 0)
                X1[nph * 512 + 480 + unit5] =
                    lstm_fin(a[0] + bt[0], a[1] + bt[1], a[2] + bt[2], a[3] + bt[3], ct);
        }
        // ---- head outputs y(t-4) (wave7, 16 lanes) ----
        if (wave == 7 && lane < 16 && t >= 4) {
            float p = wlj * (float)X1[ph * 512 + 480 + lane];
            p += __shfl_xor(p, 1, 64); p += __shfl_xor(p, 2, 64);
            p += __shfl_xor(p, 4, 64); p += __shfl_xor(p, 8, 64);
            if (lane == 0) out[(size_t)g * TT + (t - 4)] = p + blv;
        }

        __syncthreads();                     // G2 ready
        if (t <= 2047 && tid < 128) {
            float g0 = G2[tid]       + b2v[0];
            float g1 = G2[128 + tid] + b2v[1];
            float g2 = G2[256 + tid] + b2v[2];
            float g3 = G2[384 + tid] + b2v[3];
            X1[nph * 512 + 256 + tid] = lstm_fin(g0, g1, g2, g3, c2);
        }
        // ---- stage commit: h1(t+1) -> X1[nph]; post receipt ----
        if (wave == 7 && dopf) {
            const u32 want = (u32)(t + 2);
            while (!__all(((u32)(pa >> 32) == want) && ((u32)(pb >> 32) == want))) {
                pa = aload64(psrc); pb = aload64(psrc + 1);
            }
            *(u64*)(X1 + nph * 512 + 4 * lane) = (u64)(u32)pa | ((u64)(u32)pb << 32);
            if (lane == 0) apost(fBp, t + 2);
        }
        __syncthreads();                     // X1[nph] ready
    }
}

extern "C" void kernel_launch(void* const* d_in, const int* in_sizes, int n_in,
                              void* d_out, int out_size, void* d_ws, size_t ws_size,
                              hipStream_t stream) {
    const float* p[23];
    for (int i = 0; i < 23 && i < n_in; ++i) p[i] = (const float*)d_in[i];

    (void)hipFuncSetAttribute((const void*)lstm_v9,
                              hipFuncAttributeMaxDynamicSharedMemorySize,
                              LDS_BYTES);

    prep_zero<<<dim3((ZERO_F4 + 255) / 256), dim3(256), 0, stream>>>((float4*)d_ws);

    // grid 256 = CU count; ~150 KB LDS -> 1 block/CU -> all M0/M1 pairs co-resident.
    lstm_v9<<<dim3(256), dim3(512), LDS_BYTES, stream>>>(
        p[0],
        p[1],  p[2],  p[3],  p[4],
        p[5],  p[6],  p[7],  p[8],
        p[9],  p[10], p[11], p[12],
        p[13], p[14], p[15], p[16],
        p[17], p[18], p[19], p[20],
        p[21], p[22],
        (float*)d_out, (char*)d_ws);
}